// Round 7
// baseline (457.109 us; speedup 1.0000x reference)
//
#include <hip/hip_runtime.h>

#define S_LEN 16
#define NMODEL 4096
#define DHEAD 128
#define HHEADS 32
#define MCACHE 8192
#define SPLITK 16
#define KSLICE (NMODEL / SPLITK)   // 256
#define CHUNK 128                  // rows per block; 2 rows per thread in phase 1
#define NCHUNK (MCACHE / CHUNK)    // 64
#define SCPAD 17                   // odd stride -> conflict-free column reads

#define PART_ELEMS  ((size_t)3 * SPLITK * S_LEN * NMODEL)                  // 3.15M
#define OPART_ELEMS ((size_t)HHEADS * NCHUNK * S_LEN * DHEAD)              // 4.19M
#define REGION_ELEMS (PART_ELEMS > OPART_ELEMS ? PART_ELEMS : OPART_ELEMS) // max!

// ---------------- Kernel 1: split-K partial QKV projection ----------------
// Round-2 proven config: grid (8,16,3), block 256, no VGPR cap.
__global__ __launch_bounds__(256) void qkv_gemm(const float* __restrict__ X,
                                                const float* __restrict__ Wq,
                                                const float* __restrict__ Wk,
                                                const float* __restrict__ Wv,
                                                float* __restrict__ part) {
    const int tid   = threadIdx.x;
    const int col2  = blockIdx.x * 256 + tid;
    const int split = blockIdx.y;
    const int mat   = blockIdx.z;
    const float* __restrict__ W = (mat == 0) ? Wq : (mat == 1) ? Wk : Wv;
    const int k0 = split * KSLICE;

    __shared__ float Xs[KSLICE][S_LEN];     // 16 KB
    for (int i = tid; i < KSLICE * S_LEN; i += 256) {
        const int s = i & 15, k = i >> 4;
        Xs[k][s] = X[s * NMODEL + k0 + k];
    }
    __syncthreads();

    float2 acc[S_LEN];
#pragma unroll
    for (int s = 0; s < S_LEN; ++s) { acc[s].x = 0.f; acc[s].y = 0.f; }

    const float2* __restrict__ Wp = (const float2*)(W + (size_t)k0 * NMODEL) + col2;

#pragma unroll 8
    for (int k = 0; k < KSLICE; ++k) {
        const float2 w = Wp[(size_t)k * (NMODEL / 2)];
        const float4* __restrict__ xr = (const float4*)&Xs[k][0];
#pragma unroll
        for (int s4 = 0; s4 < 4; ++s4) {
            const float4 xv = xr[s4];
            acc[s4 * 4 + 0].x += xv.x * w.x;  acc[s4 * 4 + 0].y += xv.x * w.y;
            acc[s4 * 4 + 1].x += xv.y * w.x;  acc[s4 * 4 + 1].y += xv.y * w.y;
            acc[s4 * 4 + 2].x += xv.z * w.x;  acc[s4 * 4 + 2].y += xv.z * w.y;
            acc[s4 * 4 + 3].x += xv.w * w.x;  acc[s4 * 4 + 3].y += xv.w * w.y;
        }
    }

    float2* __restrict__ pp =
        (float2*)(part + (size_t)(mat * SPLITK + split) * S_LEN * NMODEL) + col2;
#pragma unroll
    for (int s = 0; s < S_LEN; ++s) pp[(size_t)s * (NMODEL / 2)] = acc[s];
}

// ---------------- Kernel 2: reduce split-K partials ----------------
__global__ __launch_bounds__(256) void qkv_reduce(const float* __restrict__ part,
                                                  float* __restrict__ qkv) {
    const int i4   = blockIdx.x * 256 + threadIdx.x;
    const int flat = i4 * 4;
    const int mat  = flat / (S_LEN * NMODEL);
    const int rem  = flat % (S_LEN * NMODEL);
    float4 sum = {0.f, 0.f, 0.f, 0.f};
#pragma unroll
    for (int sp = 0; sp < SPLITK; ++sp) {
        const float4 v = *(const float4*)(part +
            (size_t)(mat * SPLITK + sp) * (S_LEN * NMODEL) + rem);
        sum.x += v.x; sum.y += v.y; sum.z += v.z; sum.w += v.w;
    }
    *(float4*)(qkv + flat) = sum;
}

// ---------------- Kernel 3: flash-decode partial attention ----------------
// grid = (NCHUNK=64, HHEADS=32) = 2048 blocks, block = 256 (4 waves).
// 128 rows/block; phase 1 = 2 rows/thread (quad-split dims); 85-VGPR cap.
__global__ __launch_bounds__(256, 6) void attn_partial(const float* __restrict__ qkv,
                                                       const float* __restrict__ cacheK,
                                                       const float* __restrict__ cacheV,
                                                       const int* __restrict__ Pp,
                                                       float* __restrict__ opart,
                                                       float* __restrict__ mstat,
                                                       float* __restrict__ lstat) {
    const int c   = blockIdx.x;
    const int h   = blockIdx.y;
    const int tid = threadIdx.x;
    const int P   = *Pp;

    const float* qb = qkv;
    const float* kb = qkv + S_LEN * NMODEL;
    const float* vb = qkv + 2 * S_LEN * NMODEL;

    __shared__ float q_s[S_LEN][DHEAD];      // 8 KB
    __shared__ float sc[CHUNK][SCPAD];       // 8.7 KB
    __shared__ float mloc[S_LEN], lloc[S_LEN];

    for (int i = tid; i < S_LEN * DHEAD; i += 256)
        q_s[i >> 7][i & 127] = qb[(i >> 7) * NMODEL + h * DHEAD + (i & 127)];
    __syncthreads();

    // ---- phase 1: scores; thread quad = (rows r, r+64; dims sub*4 per j) ----
    {
        const int sub = tid & 3;
        const int r   = tid >> 2;            // 0..63
        const int gm0 = c * CHUNK + r;
        const int gm1 = gm0 + 64;
        const float* kr0 = (gm0 >= P && gm0 < P + S_LEN)
            ? kb + (size_t)(gm0 - P) * NMODEL + h * DHEAD
            : cacheK + ((size_t)h * MCACHE + gm0) * DHEAD;
        const float* kr1 = (gm1 >= P && gm1 < P + S_LEN)
            ? kb + (size_t)(gm1 - P) * NMODEL + h * DHEAD
            : cacheK + ((size_t)h * MCACHE + gm1) * DHEAD;

        float acc0[S_LEN], acc1[S_LEN];
#pragma unroll
        for (int s = 0; s < S_LEN; ++s) { acc0[s] = 0.f; acc1[s] = 0.f; }

#pragma unroll
        for (int j = 0; j < 8; ++j) {
            const float4 kv0 = *(const float4*)(kr0 + j * 16 + sub * 4);
            const float4 kv1 = *(const float4*)(kr1 + j * 16 + sub * 4);
#pragma unroll
            for (int s = 0; s < S_LEN; ++s) {
                const float4 qv = *(const float4*)&q_s[s][j * 16 + sub * 4];
                acc0[s] += kv0.x * qv.x + kv0.y * qv.y + kv0.z * qv.z + kv0.w * qv.w;
                acc1[s] += kv1.x * qv.x + kv1.y * qv.y + kv1.z * qv.z + kv1.w * qv.w;
            }
        }
#pragma unroll
        for (int s = 0; s < S_LEN; ++s) {
            float v0 = acc0[s], v1 = acc1[s];
            v0 += __shfl_xor(v0, 1, 64); v0 += __shfl_xor(v0, 2, 64);
            v1 += __shfl_xor(v1, 1, 64); v1 += __shfl_xor(v1, 2, 64);
            acc0[s] = v0; acc1[s] = v1;
        }
        if (sub == 0) {
#pragma unroll
            for (int s = 0; s < S_LEN; ++s) {
                sc[r][s]      = acc0[s];
                sc[r + 64][s] = acc1[s];
            }
        }
    }
    __syncthreads();

    // ---- phase 2: per-s max & sumexp over 128 rows (2 per lane) ----
    {
        const int wv = tid >> 6, lane = tid & 63;
#pragma unroll
        for (int si = 0; si < 4; ++si) {
            const int s = wv * 4 + si;
            const float v0 = sc[lane][s];
            const float v1 = sc[lane + 64][s];
            float mx = fmaxf(v0, v1);
            for (int off = 32; off > 0; off >>= 1) mx = fmaxf(mx, __shfl_xor(mx, off, 64));
            const float e0 = __expf(v0 - mx);
            const float e1 = __expf(v1 - mx);
            sc[lane][s] = e0; sc[lane + 64][s] = e1;
            float sum = e0 + e1;
            for (int off = 32; off > 0; off >>= 1) sum += __shfl_xor(sum, off, 64);
            if (lane == 0) { mloc[s] = mx; lloc[s] = sum; }
        }
    }
    __syncthreads();

    // ---- phase 3: o[s][d] = sum_m p*V ; unrolled x2, loads staged ----
    {
        const int s  = tid >> 4;
        const int d0 = (tid & 15) * 8;
        float a[8];
#pragma unroll
        for (int j = 0; j < 8; ++j) a[j] = 0.f;

        for (int m = 0; m < CHUNK; m += 2) {
            const int gm0 = c * CHUNK + m;
            const int gm1 = gm0 + 1;
            const float* vr0 = (gm0 >= P && gm0 < P + S_LEN)
                ? vb + (size_t)(gm0 - P) * NMODEL + h * DHEAD
                : cacheV + ((size_t)h * MCACHE + gm0) * DHEAD;
            const float* vr1 = (gm1 >= P && gm1 < P + S_LEN)
                ? vb + (size_t)(gm1 - P) * NMODEL + h * DHEAD
                : cacheV + ((size_t)h * MCACHE + gm1) * DHEAD;
            const float4 v00 = *(const float4*)(vr0 + d0);
            const float4 v01 = *(const float4*)(vr0 + d0 + 4);
            const float4 v10 = *(const float4*)(vr1 + d0);
            const float4 v11 = *(const float4*)(vr1 + d0 + 4);
            const float p0 = sc[m][s];
            const float p1 = sc[m + 1][s];
            a[0] += p0 * v00.x; a[1] += p0 * v00.y; a[2] += p0 * v00.z; a[3] += p0 * v00.w;
            a[4] += p0 * v01.x; a[5] += p0 * v01.y; a[6] += p0 * v01.z; a[7] += p0 * v01.w;
            a[0] += p1 * v10.x; a[1] += p1 * v10.y; a[2] += p1 * v10.z; a[3] += p1 * v10.w;
            a[4] += p1 * v11.x; a[5] += p1 * v11.y; a[6] += p1 * v11.z; a[7] += p1 * v11.w;
        }
        const size_t ob = (((size_t)h * NCHUNK + c) * S_LEN + s) * DHEAD + d0;
        float4 w0; w0.x = a[0]; w0.y = a[1]; w0.z = a[2]; w0.w = a[3];
        float4 w1; w1.x = a[4]; w1.y = a[5]; w1.z = a[6]; w1.w = a[7];
        *(float4*)(opart + ob)     = w0;
        *(float4*)(opart + ob + 4) = w1;
    }
    if (tid < S_LEN) {
        mstat[((size_t)h * NCHUNK + c) * S_LEN + tid] = mloc[tid];
        lstat[((size_t)h * NCHUNK + c) * S_LEN + tid] = lloc[tid];
    }
}

// ---------------- Kernel 4: combine chunk partials ----------------
__global__ __launch_bounds__(128) void attn_combine(const float* __restrict__ opart,
                                                    const float* __restrict__ mstat,
                                                    const float* __restrict__ lstat,
                                                    float* __restrict__ out) {
    const int d = threadIdx.x;
    const int s = blockIdx.x;
    const int h = blockIdx.y;

    float gmax = -1e30f;
#pragma unroll 8
    for (int c = 0; c < NCHUNK; ++c)
        gmax = fmaxf(gmax, mstat[((size_t)h * NCHUNK + c) * S_LEN + s]);

    float L = 0.f, o = 0.f;
#pragma unroll 4
    for (int c = 0; c < NCHUNK; ++c) {
        const size_t si = (size_t)h * NCHUNK * S_LEN + (size_t)c * S_LEN + s;
        const float w = __expf(mstat[si] - gmax);
        L += lstat[si] * w;
        o += w * opart[si * DHEAD + d];
    }
    out[((size_t)h * S_LEN + s) * DHEAD + d] = o / L;
}

extern "C" void kernel_launch(void* const* d_in, const int* in_sizes, int n_in,
                              void* d_out, int out_size, void* d_ws, size_t ws_size,
                              hipStream_t stream) {
    const float* X      = (const float*)d_in[0];
    const float* Wq     = (const float*)d_in[1];
    const float* Wk     = (const float*)d_in[2];
    const float* Wv     = (const float*)d_in[3];
    const float* cacheK = (const float*)d_in[4];
    const float* cacheV = (const float*)d_in[5];
    const int*   P      = (const int*)d_in[6];
    float* out = (float*)d_out;
    float* ws  = (float*)d_ws;

    // ws layout (floats). opart ALIASES part (part is dead after qkv_reduce).
    // CRITICAL: mstat goes after max(PART_ELEMS, OPART_ELEMS) — round-6 bug
    // was placing it at PART_ELEMS (3.15M) inside opart (4.19M) -> clobbered.
    float* qkv   = ws;                                   // 196608 floats
    float* part  = qkv + 3 * S_LEN * NMODEL;
    float* opart = part;
    float* mstat = part + REGION_ELEMS;
    float* lstat = mstat + (size_t)HHEADS * NCHUNK * S_LEN;

    qkv_gemm<<<dim3(8, SPLITK, 3), 256, 0, stream>>>(X, Wq, Wk, Wv, part);
    qkv_reduce<<<(3 * S_LEN * NMODEL / 4) / 256, 256, 0, stream>>>(part, qkv);
    attn_partial<<<dim3(NCHUNK, HHEADS), 256, 0, stream>>>(qkv, cacheK, cacheV, P,
                                                           opart, mstat, lstat);
    attn_combine<<<dim3(S_LEN, HHEADS), DHEAD, 0, stream>>>(opart, mstat, lstat, out);
}

// Round 8
// 262.744 us; speedup vs baseline: 1.7397x; 1.7397x over previous
//
#include <hip/hip_runtime.h>

#define S_LEN 16
#define NMODEL 4096
#define DHEAD 128
#define HHEADS 32
#define MCACHE 8192
#define SPLITK 16
#define KSLICE (NMODEL / SPLITK)   // 256
#define CHUNK 128
#define NCHUNK (MCACHE / CHUNK)    // 64
#define M_PAD 132                  // sct row stride: 528 B, 16B-aligned, bank-offset 4

#define PART_ELEMS  ((size_t)3 * SPLITK * S_LEN * NMODEL)                  // 3.15M
#define OPART_ELEMS ((size_t)HHEADS * NCHUNK * S_LEN * DHEAD)              // 4.19M
#define REGION_ELEMS (PART_ELEMS > OPART_ELEMS ? PART_ELEMS : OPART_ELEMS)

// ---------------- Kernel 1: split-K partial QKV projection ----------------
__global__ __launch_bounds__(256) void qkv_gemm(const float* __restrict__ X,
                                                const float* __restrict__ Wq,
                                                const float* __restrict__ Wk,
                                                const float* __restrict__ Wv,
                                                float* __restrict__ part) {
    const int tid   = threadIdx.x;
    const int col2  = blockIdx.x * 256 + tid;
    const int split = blockIdx.y;
    const int mat   = blockIdx.z;
    const float* __restrict__ W = (mat == 0) ? Wq : (mat == 1) ? Wk : Wv;
    const int k0 = split * KSLICE;

    __shared__ float Xs[KSLICE][S_LEN];     // 16 KB
    for (int i = tid; i < KSLICE * S_LEN; i += 256) {
        const int s = i & 15, k = i >> 4;
        Xs[k][s] = X[s * NMODEL + k0 + k];
    }
    __syncthreads();

    float2 acc[S_LEN];
#pragma unroll
    for (int s = 0; s < S_LEN; ++s) { acc[s].x = 0.f; acc[s].y = 0.f; }

    const float2* __restrict__ Wp = (const float2*)(W + (size_t)k0 * NMODEL) + col2;

#pragma unroll 8
    for (int k = 0; k < KSLICE; ++k) {
        const float2 w = Wp[(size_t)k * (NMODEL / 2)];
        const float4* __restrict__ xr = (const float4*)&Xs[k][0];
#pragma unroll
        for (int s4 = 0; s4 < 4; ++s4) {
            const float4 xv = xr[s4];
            acc[s4 * 4 + 0].x += xv.x * w.x;  acc[s4 * 4 + 0].y += xv.x * w.y;
            acc[s4 * 4 + 1].x += xv.y * w.x;  acc[s4 * 4 + 1].y += xv.y * w.y;
            acc[s4 * 4 + 2].x += xv.z * w.x;  acc[s4 * 4 + 2].y += xv.z * w.y;
            acc[s4 * 4 + 3].x += xv.w * w.x;  acc[s4 * 4 + 3].y += xv.w * w.y;
        }
    }

    float2* __restrict__ pp =
        (float2*)(part + (size_t)(mat * SPLITK + split) * S_LEN * NMODEL) + col2;
#pragma unroll
    for (int s = 0; s < S_LEN; ++s) pp[(size_t)s * (NMODEL / 2)] = acc[s];
}

// ---------------- Kernel 2: reduce split-K partials ----------------
__global__ __launch_bounds__(256) void qkv_reduce(const float* __restrict__ part,
                                                  float* __restrict__ qkv) {
    const int i4   = blockIdx.x * 256 + threadIdx.x;
    const int flat = i4 * 4;
    const int mat  = flat / (S_LEN * NMODEL);
    const int rem  = flat % (S_LEN * NMODEL);
    float4 sum = {0.f, 0.f, 0.f, 0.f};
#pragma unroll
    for (int sp = 0; sp < SPLITK; ++sp) {
        const float4 v = *(const float4*)(part +
            (size_t)(mat * SPLITK + sp) * (S_LEN * NMODEL) + rem);
        sum.x += v.x; sum.y += v.y; sum.z += v.z; sum.w += v.w;
    }
    *(float4*)(qkv + flat) = sum;
}

// ---------------- Kernel 3: flash-decode partial attention ----------------
// grid = (NCHUNK=64, HHEADS=32) = 2048 blocks, block 256 (4 waves).
// Wave wv owns s = wv*4 + (lane>>4); lane's dslice = lane&15 covers 8 dims.
// q lives in 8 registers per lane; K-stream has ZERO LDS reads.
__global__ __launch_bounds__(256) void attn_partial(const float* __restrict__ qkv,
                                                    const float* __restrict__ cacheK,
                                                    const float* __restrict__ cacheV,
                                                    const int* __restrict__ Pp,
                                                    float* __restrict__ opart,
                                                    float* __restrict__ mstat,
                                                    float* __restrict__ lstat) {
    const int c    = blockIdx.x;
    const int h    = blockIdx.y;
    const int tid  = threadIdx.x;
    const int wv   = tid >> 6;
    const int lane = tid & 63;
    const int P    = *Pp;

    const float* qb = qkv;
    const float* kb = qkv + S_LEN * NMODEL;
    const float* vb = qkv + 2 * S_LEN * NMODEL;

    __shared__ float sct[S_LEN][M_PAD];      // 8.4 KB, transposed scores
    __shared__ float mloc[S_LEN], lloc[S_LEN];

    // ---- phase 1: scores. q in regs; packed K loads; butterfly dot ----
    {
        const int s_mine = wv * 4 + (lane >> 4);
        const int dsl    = lane & 15;
        const int doff   = dsl * 8;
        const float4 q0 = *(const float4*)(qb + s_mine * NMODEL + h * DHEAD + doff);
        const float4 q1 = *(const float4*)(qb + s_mine * NMODEL + h * DHEAD + doff + 4);

        for (int m = 0; m < CHUNK; m += 4) {
            float part4[4];
#pragma unroll
            for (int i = 0; i < 4; ++i) {
                const int gm = c * CHUNK + m + i;
                const float* kr = (gm >= P && gm < P + S_LEN)
                    ? kb + (size_t)(gm - P) * NMODEL + h * DHEAD
                    : cacheK + ((size_t)h * MCACHE + gm) * DHEAD;
                const float4 k0 = *(const float4*)(kr + doff);
                const float4 k1 = *(const float4*)(kr + doff + 4);
                part4[i] = k0.x * q0.x + k0.y * q0.y + k0.z * q0.z + k0.w * q0.w
                         + k1.x * q1.x + k1.y * q1.y + k1.z * q1.z + k1.w * q1.w;
            }
#pragma unroll
            for (int i = 0; i < 4; ++i) {
                float v = part4[i];
                v += __shfl_xor(v, 1, 64);
                v += __shfl_xor(v, 2, 64);
                v += __shfl_xor(v, 4, 64);
                v += __shfl_xor(v, 8, 64);
                part4[i] = v;
            }
            if (dsl == 0) {
#pragma unroll
                for (int i = 0; i < 4; ++i) sct[s_mine][m + i] = part4[i];
            }
        }
    }
    __syncthreads();

    // ---- phase 2: per-s max & sumexp over 128 rows (transposed layout) ----
    {
#pragma unroll
        for (int si = 0; si < 4; ++si) {
            const int s = wv * 4 + si;
            const float v0 = sct[s][lane];
            const float v1 = sct[s][lane + 64];
            float mx = fmaxf(v0, v1);
            for (int off = 32; off > 0; off >>= 1) mx = fmaxf(mx, __shfl_xor(mx, off, 64));
            const float e0 = __expf(v0 - mx);
            const float e1 = __expf(v1 - mx);
            sct[s][lane] = e0; sct[s][lane + 64] = e1;
            float sum = e0 + e1;
            for (int off = 32; off > 0; off >>= 1) sum += __shfl_xor(sum, off, 64);
            if (lane == 0) { mloc[s] = mx; lloc[s] = sum; }
        }
    }
    __syncthreads();

    // ---- phase 3: o[s][d] = sum_m p*V ; p via float4 from sct[s][m] ----
    {
        const int s  = tid >> 4;
        const int d0 = (tid & 15) * 8;
        float a[8];
#pragma unroll
        for (int j = 0; j < 8; ++j) a[j] = 0.f;

        for (int m = 0; m < CHUNK; m += 4) {
            const float4 p4 = *(const float4*)&sct[s][m];   // broadcast within s-group
#pragma unroll
            for (int i = 0; i < 4; ++i) {
                const int gm = c * CHUNK + m + i;
                const float* vr = (gm >= P && gm < P + S_LEN)
                    ? vb + (size_t)(gm - P) * NMODEL + h * DHEAD
                    : cacheV + ((size_t)h * MCACHE + gm) * DHEAD;
                const float p = (i == 0) ? p4.x : (i == 1) ? p4.y : (i == 2) ? p4.z : p4.w;
                const float4 v0 = *(const float4*)(vr + d0);
                const float4 v1 = *(const float4*)(vr + d0 + 4);
                a[0] += p * v0.x; a[1] += p * v0.y; a[2] += p * v0.z; a[3] += p * v0.w;
                a[4] += p * v1.x; a[5] += p * v1.y; a[6] += p * v1.z; a[7] += p * v1.w;
            }
        }
        const size_t ob = (((size_t)h * NCHUNK + c) * S_LEN + s) * DHEAD + d0;
        float4 w0; w0.x = a[0]; w0.y = a[1]; w0.z = a[2]; w0.w = a[3];
        float4 w1; w1.x = a[4]; w1.y = a[5]; w1.z = a[6]; w1.w = a[7];
        *(float4*)(opart + ob)     = w0;
        *(float4*)(opart + ob + 4) = w1;
    }
    if (tid < S_LEN) {
        mstat[((size_t)h * NCHUNK + c) * S_LEN + tid] = mloc[tid];
        lstat[((size_t)h * NCHUNK + c) * S_LEN + tid] = lloc[tid];
    }
}

// ---------------- Kernel 4: combine chunk partials ----------------
__global__ __launch_bounds__(128) void attn_combine(const float* __restrict__ opart,
                                                    const float* __restrict__ mstat,
                                                    const float* __restrict__ lstat,
                                                    float* __restrict__ out) {
    const int d = threadIdx.x;
    const int s = blockIdx.x;
    const int h = blockIdx.y;

    float gmax = -1e30f;
#pragma unroll 8
    for (int c = 0; c < NCHUNK; ++c)
        gmax = fmaxf(gmax, mstat[((size_t)h * NCHUNK + c) * S_LEN + s]);

    float L = 0.f, o = 0.f;
#pragma unroll 4
    for (int c = 0; c < NCHUNK; ++c) {
        const size_t si = (size_t)h * NCHUNK * S_LEN + (size_t)c * S_LEN + s;
        const float w = __expf(mstat[si] - gmax);
        L += lstat[si] * w;
        o += w * opart[si * DHEAD + d];
    }
    out[((size_t)h * S_LEN + s) * DHEAD + d] = o / L;
}

extern "C" void kernel_launch(void* const* d_in, const int* in_sizes, int n_in,
                              void* d_out, int out_size, void* d_ws, size_t ws_size,
                              hipStream_t stream) {
    const float* X      = (const float*)d_in[0];
    const float* Wq     = (const float*)d_in[1];
    const float* Wk     = (const float*)d_in[2];
    const float* Wv     = (const float*)d_in[3];
    const float* cacheK = (const float*)d_in[4];
    const float* cacheV = (const float*)d_in[5];
    const int*   P      = (const int*)d_in[6];
    float* out = (float*)d_out;
    float* ws  = (float*)d_ws;

    // ws layout (floats). opart ALIASES part; mstat after max of both regions.
    float* qkv   = ws;                                   // 196608 floats
    float* part  = qkv + 3 * S_LEN * NMODEL;
    float* opart = part;
    float* mstat = part + REGION_ELEMS;
    float* lstat = mstat + (size_t)HHEADS * NCHUNK * S_LEN;

    qkv_gemm<<<dim3(8, SPLITK, 3), 256, 0, stream>>>(X, Wq, Wk, Wv, part);
    qkv_reduce<<<(3 * S_LEN * NMODEL / 4) / 256, 256, 0, stream>>>(part, qkv);
    attn_partial<<<dim3(NCHUNK, HHEADS), 256, 0, stream>>>(qkv, cacheK, cacheV, P,
                                                           opart, mstat, lstat);
    attn_combine<<<dim3(S_LEN, HHEADS), DHEAD, 0, stream>>>(opart, mstat, lstat, out);
}